// Round 1
// baseline (9428.986 us; speedup 1.0000x reference)
//
#include <hip/hip_runtime.h>

#define N_NODESC 50000
#define N_EDGESC 800000
#define N_GRAPHSC 128
#define EMBEDC 256

// ---------------------------------------------------------------- atom encoder
__global__ __launch_bounds__(256) void atom_encode_k(
    const int* __restrict__ nfeat, const float* __restrict__ atom_emb,
    float* __restrict__ h)
{
  int w = threadIdx.x >> 6, lane = threadIdx.x & 63;
  int n = blockIdx.x * 4 + w;
  if (n >= N_NODESC) return;
  const int* nf = nfeat + n * 9;
  float4 acc = make_float4(0.f, 0.f, 0.f, 0.f);
#pragma unroll
  for (int c = 0; c < 9; ++c) {
    int idx = nf[c];
    const float4* row = (const float4*)(atom_emb + (c * 128 + idx) * EMBEDC);
    float4 v = row[lane];
    acc.x += v.x; acc.y += v.y; acc.z += v.z; acc.w += v.w;
  }
  ((float4*)(h + (long)n * EMBEDC))[lane] = acc;
}

// ------------------------------------------------- degree count + edge histogram
__global__ __launch_bounds__(256) void deg_hist_k(
    const int* __restrict__ dst, const int* __restrict__ efeat,
    int* __restrict__ degs, int* __restrict__ cnt)
{
  int e = blockIdx.x * 256 + threadIdx.x;
  if (e >= N_EDGESC) return;
  int d = dst[e];
  atomicAdd(&degs[d], 1);
  int base = d * 24;
#pragma unroll
  for (int c = 0; c < 3; ++c) {
    int v = efeat[e * 3 + c];
    atomicAdd(&cnt[base + c * 8 + v], 1);
  }
}

// ---------------------------------------------------------------- exclusive scan
__global__ __launch_bounds__(1024) void scan_k(
    const int* __restrict__ deg, int* __restrict__ row_start, int n)
{
  __shared__ int buf[1024];
  __shared__ int carry;
  int t = threadIdx.x;
  if (t == 0) carry = 0;
  __syncthreads();
  for (int base = 0; base < n; base += 8192) {
    int loc[8];
    int s = 0;
    int idx0 = base + t * 8;
#pragma unroll
    for (int i = 0; i < 8; ++i) {
      int v = (idx0 + i < n) ? deg[idx0 + i] : 0;
      loc[i] = v; s += v;
    }
    buf[t] = s;
    __syncthreads();
    for (int off = 1; off < 1024; off <<= 1) {
      int add = (t >= off) ? buf[t - off] : 0;
      __syncthreads();
      buf[t] += add;
      __syncthreads();
    }
    int excl = buf[t] - s;
    int run = carry + excl;
#pragma unroll
    for (int i = 0; i < 8; ++i) {
      if (idx0 + i < n) row_start[idx0 + i] = run;
      run += loc[i];
    }
    __syncthreads();
    if (t == 1023) carry += buf[1023];
    __syncthreads();
  }
  if (t == 0) row_start[n] = carry;
}

// ---------------------------------------------------------------- CSR scatter
__global__ __launch_bounds__(256) void scatter_k(
    const int* __restrict__ src, const int* __restrict__ dst,
    const int* __restrict__ row_start, int* __restrict__ fill,
    int* __restrict__ csr)
{
  int e = blockIdx.x * 256 + threadIdx.x;
  if (e >= N_EDGESC) return;
  int d = dst[e];
  int pos = row_start[d] + atomicAdd(&fill[d], 1);
  csr[pos] = src[e];
}

// ---------------------------------------------------------------- aggregation
// x[n] = (h[n] + sum_{e in in(n)} h[src[e]] + sum_j cnt[n][j]*emb_l[j]) / (deg+1)
__global__ __launch_bounds__(256) void aggregate_k(
    const float* __restrict__ h, const float* __restrict__ emb_l,
    const int* __restrict__ csr, const int* __restrict__ row_start,
    const int* __restrict__ cnt, float* __restrict__ x)
{
  __shared__ float semb[24 * EMBEDC];
  for (int i = threadIdx.x; i < 24 * EMBEDC; i += 256) semb[i] = emb_l[i];
  __syncthreads();
  int w = threadIdx.x >> 6, lane = threadIdx.x & 63;
  int n = blockIdx.x * 4 + w;
  if (n >= N_NODESC) return;
  float4 acc = ((const float4*)(h + (long)n * EMBEDC))[lane];
  int s0 = row_start[n], s1 = row_start[n + 1];
  int e = s0;
  for (; e + 4 <= s1; e += 4) {
    int i0 = csr[e], i1 = csr[e + 1], i2 = csr[e + 2], i3 = csr[e + 3];
    float4 v0 = ((const float4*)(h + (long)i0 * EMBEDC))[lane];
    float4 v1 = ((const float4*)(h + (long)i1 * EMBEDC))[lane];
    float4 v2 = ((const float4*)(h + (long)i2 * EMBEDC))[lane];
    float4 v3 = ((const float4*)(h + (long)i3 * EMBEDC))[lane];
    acc.x += v0.x + v1.x + v2.x + v3.x;
    acc.y += v0.y + v1.y + v2.y + v3.y;
    acc.z += v0.z + v1.z + v2.z + v3.z;
    acc.w += v0.w + v1.w + v2.w + v3.w;
  }
  for (; e < s1; ++e) {
    int i0 = csr[e];
    float4 v0 = ((const float4*)(h + (long)i0 * EMBEDC))[lane];
    acc.x += v0.x; acc.y += v0.y; acc.z += v0.z; acc.w += v0.w;
  }
  const int* cn = cnt + n * 24;
#pragma unroll
  for (int j = 0; j < 24; ++j) {
    int cj = cn[j];
    if (cj) {
      float fc = (float)cj;
      float4 ev = ((const float4*)(semb + j * EMBEDC))[lane];
      acc.x += fc * ev.x; acc.y += fc * ev.y;
      acc.z += fc * ev.z; acc.w += fc * ev.w;
    }
  }
  float inv = 1.0f / (float)(s1 - s0 + 1);
  float4 o;
  o.x = acc.x * inv; o.y = acc.y * inv; o.z = acc.z * inv; o.w = acc.w * inv;
  ((float4*)(x + (long)n * EMBEDC))[lane] = o;
}

// ---------------------------------------------------------------- GEMM + BN stats
// y = x @ W + b ; colsum/colsumsq accumulated for BN
__global__ __launch_bounds__(256) void gemm_bn_k(
    const float* __restrict__ X, const float* __restrict__ Wl,
    const float* __restrict__ bl, float* __restrict__ Y,
    float* __restrict__ colsum, float* __restrict__ colsumsq, int n_rows)
{
  __shared__ float xsT[16 * 128];
  __shared__ float ws[16 * 144];
  int t = threadIdx.x;
  int row0 = blockIdx.x * 128;
  int nc0 = blockIdx.y * 128;
  int tm = t >> 4, tn = t & 15;
  float acc[8][8];
#pragma unroll
  for (int i = 0; i < 8; ++i)
#pragma unroll
    for (int j = 0; j < 8; ++j) acc[i][j] = 0.f;

  for (int kc = 0; kc < 256; kc += 16) {
#pragma unroll
    for (int q = 0; q < 2; ++q) {
      int id = t + (q << 8);
      int kq = id & 3, m = id >> 2;
      int row = row0 + m;
      float4 v = make_float4(0.f, 0.f, 0.f, 0.f);
      if (row < n_rows) v = *(const float4*)(X + (long)row * 256 + kc + (kq << 2));
      xsT[(kq * 4 + 0) * 128 + m] = v.x;
      xsT[(kq * 4 + 1) * 128 + m] = v.y;
      xsT[(kq * 4 + 2) * 128 + m] = v.z;
      xsT[(kq * 4 + 3) * 128 + m] = v.w;
    }
#pragma unroll
    for (int q = 0; q < 2; ++q) {
      int id = t + (q << 8);
      int k = id >> 5, nf = (id & 31) << 2;
      float4 v = *(const float4*)(Wl + (long)(kc + k) * 256 + nc0 + nf);
      *(float4*)&ws[k * 144 + nf + ((nf >> 5) << 2)] = v;
    }
    __syncthreads();
#pragma unroll
    for (int k = 0; k < 16; ++k) {
      float4 a0 = *(const float4*)&xsT[k * 128 + tm * 8];
      float4 a1 = *(const float4*)&xsT[k * 128 + tm * 8 + 4];
      int bo = tn * 8 + ((tn >> 2) << 2);
      float4 b0 = *(const float4*)&ws[k * 144 + bo];
      float4 b1 = *(const float4*)&ws[k * 144 + bo + 4];
      float a[8] = {a0.x, a0.y, a0.z, a0.w, a1.x, a1.y, a1.z, a1.w};
      float bb[8] = {b0.x, b0.y, b0.z, b0.w, b1.x, b1.y, b1.z, b1.w};
#pragma unroll
      for (int i = 0; i < 8; ++i)
#pragma unroll
        for (int j = 0; j < 8; ++j) acc[i][j] += a[i] * bb[j];
    }
    __syncthreads();
  }

  float bj[8];
#pragma unroll
  for (int j = 0; j < 8; ++j) bj[j] = bl[nc0 + tn * 8 + j];
#pragma unroll
  for (int j = 0; j < 8; ++j) {
    int col = nc0 + tn * 8 + j;
    float s = 0.f, s2 = 0.f;
#pragma unroll
    for (int i = 0; i < 8; ++i) {
      int row = row0 + tm * 8 + i;
      if (row < n_rows) {
        float v = acc[i][j] + bj[j];
        Y[(long)row * 256 + col] = v;
        s += v; s2 += v * v;
      }
    }
    atomicAdd(&colsum[col], s);
    atomicAdd(&colsumsq[col], s2);
  }
}

// ---------------------------------------------------------------- BN finalize
__global__ void bn_finalize_k(
    float* __restrict__ colsum, float* __restrict__ colsumsq,
    const float* __restrict__ gamma, const float* __restrict__ beta,
    float* __restrict__ scale, float* __restrict__ shiftv)
{
  int t = threadIdx.x;
  float cs = colsum[t], cq = colsumsq[t];
  const float invN = 1.0f / (float)N_NODESC;
  float mu = cs * invN;
  float var = cq * invN - mu * mu;
  float rs = rsqrtf(var + 1e-5f);
  float sc = gamma[t] * rs;
  scale[t] = sc;
  shiftv[t] = beta[t] - mu * sc;
  colsum[t] = 0.f;
  colsumsq[t] = 0.f;
}

// ---------------------------------------------------------------- BN apply + relu
__global__ __launch_bounds__(256) void bn_relu_k(
    float* __restrict__ y, const float* __restrict__ scale,
    const float* __restrict__ shiftv)
{
  int i = blockIdx.x * 256 + threadIdx.x;  // float4 index, 3.2M total
  int d = i & 63;
  float4 v = ((float4*)y)[i];
  float4 sc = ((const float4*)scale)[d];
  float4 sh = ((const float4*)shiftv)[d];
  v.x = fmaxf(0.f, v.x * sc.x + sh.x);
  v.y = fmaxf(0.f, v.y * sc.y + sh.y);
  v.z = fmaxf(0.f, v.z * sc.z + sh.z);
  v.w = fmaxf(0.f, v.w * sc.w + sh.w);
  ((float4*)y)[i] = v;
}

// ---------------------------------------------------------------- mean pooling
__device__ __forceinline__ int lower_bound_g(const int* gid, int n, int g)
{
  int lo = 0, hi = n;
  while (lo < hi) {
    int mid = (lo + hi) >> 1;
    if (gid[mid] < g) lo = mid + 1; else hi = mid;
  }
  return lo;
}

__global__ __launch_bounds__(256) void pool_k(
    const float* __restrict__ h, const int* __restrict__ gid,
    float* __restrict__ gpool)
{
  int g = blockIdx.x;
  int lo = lower_bound_g(gid, N_NODESC, g);
  int hi = lower_bound_g(gid, N_NODESC, g + 1);
  int c = hi - lo;
  float inv = 1.0f / (float)(c > 0 ? c : 1);
  int d = threadIdx.x;
  float acc = 0.f;
  for (int r = lo; r < hi; ++r) acc += h[(long)r * EMBEDC + d];
  gpool[g * EMBEDC + d] = acc * inv;
}

// ---------------------------------------------------------------- final proj
__global__ __launch_bounds__(128) void final_k(
    const float* __restrict__ gpool, const float* __restrict__ Wp,
    const float* __restrict__ bp, float* __restrict__ out)
{
  __shared__ float gr[256];
  int g = blockIdx.x, t = threadIdx.x;
  gr[t] = gpool[g * 256 + t];
  gr[t + 128] = gpool[g * 256 + t + 128];
  __syncthreads();
  float acc = bp[t];
#pragma unroll 8
  for (int k = 0; k < 256; ++k) acc += gr[k] * Wp[k * 128 + t];
  out[g * 128 + t] = acc;
}

// ---------------------------------------------------------------- launcher
extern "C" void kernel_launch(void* const* d_in, const int* in_sizes, int n_in,
                              void* d_out, int out_size, void* d_ws, size_t ws_size,
                              hipStream_t stream)
{
  (void)in_sizes; (void)n_in; (void)out_size; (void)ws_size;
  const int* nfeat = (const int*)d_in[0];
  const int* efeat = (const int*)d_in[1];
  const int* src = (const int*)d_in[2];
  const int* dst = (const int*)d_in[3];
  const int* gid = (const int*)d_in[4];
  const float* atom_emb = (const float*)d_in[5];
  const float* edge_emb = (const float*)d_in[6];
  const float* W = (const float*)d_in[7];
  const float* b = (const float*)d_in[8];
  const float* gamma = (const float*)d_in[9];
  const float* beta = (const float*)d_in[10];
  const float* Wp = (const float*)d_in[11];
  const float* bp = (const float*)d_in[12];
  float* out = (float*)d_out;

  char* ws = (char*)d_ws;
  float* A = (float*)ws; ws += 51200000;       // h / y (aliased)
  float* X = (float*)ws; ws += 51200000;       // aggregate output
  int* csr = (int*)ws; ws += 3200000;
  int* row_start = (int*)ws; ws += 200064;
  int* degs_i = (int*)ws; ws += 200064;
  int* fill = (int*)ws; ws += 200064;
  int* cnt = (int*)ws; ws += 4800000;
  float* colsum = (float*)ws; ws += 1024;
  float* colsumsq = (float*)ws; ws += 1024;
  float* scale = (float*)ws; ws += 1024;
  float* shiftv = (float*)ws; ws += 1024;
  float* gpool = (float*)ws; ws += 131072;

  hipMemsetAsync(degs_i, 0, 200000, stream);
  hipMemsetAsync(fill, 0, 200000, stream);
  hipMemsetAsync(cnt, 0, 4800000, stream);
  hipMemsetAsync(colsum, 0, 2048, stream);  // colsum + colsumsq contiguous

  atom_encode_k<<<12500, 256, 0, stream>>>(nfeat, atom_emb, A);
  deg_hist_k<<<3125, 256, 0, stream>>>(dst, efeat, degs_i, cnt);
  scan_k<<<1, 1024, 0, stream>>>(degs_i, row_start, N_NODESC);
  scatter_k<<<3125, 256, 0, stream>>>(src, dst, row_start, fill, csr);

  for (int l = 0; l < 5; ++l) {
    aggregate_k<<<12500, 256, 0, stream>>>(A, edge_emb + l * 6144, csr,
                                           row_start, cnt, X);
    gemm_bn_k<<<dim3(391, 2), 256, 0, stream>>>(X, W + l * 65536, b + l * 256,
                                                A, colsum, colsumsq, N_NODESC);
    bn_finalize_k<<<1, 256, 0, stream>>>(colsum, colsumsq, gamma + l * 256,
                                         beta + l * 256, scale, shiftv);
    bn_relu_k<<<12500, 256, 0, stream>>>(A, scale, shiftv);
  }

  pool_k<<<128, 256, 0, stream>>>(A, gid, gpool);
  final_k<<<128, 128, 0, stream>>>(gpool, Wp, bp, out);
}

// Round 2
// 1738.008 us; speedup vs baseline: 5.4252x; 5.4252x over previous
//
#include <hip/hip_runtime.h>

#define N_NODESC 50000
#define N_PAD 50176          // 392 * 128
#define N_EDGESC 800000
#define N_GRAPHSC 128
#define EMBEDC 256
#define MTILES 392

// ---------------------------------------------------------------- atom encoder
__global__ __launch_bounds__(256) void atom_encode_k(
    const int* __restrict__ nfeat, const float* __restrict__ atom_emb,
    float* __restrict__ h)
{
  int w = threadIdx.x >> 6, lane = threadIdx.x & 63;
  int n = blockIdx.x * 4 + w;
  if (n >= N_NODESC) return;
  const int* nf = nfeat + n * 9;
  float4 acc = make_float4(0.f, 0.f, 0.f, 0.f);
#pragma unroll
  for (int c = 0; c < 9; ++c) {
    int idx = nf[c];
    const float4* row = (const float4*)(atom_emb + (c * 128 + idx) * EMBEDC);
    float4 v = row[lane];
    acc.x += v.x; acc.y += v.y; acc.z += v.z; acc.w += v.w;
  }
  ((float4*)(h + (long)n * EMBEDC))[lane] = acc;
}

// ------------------------------------------------- degree count + edge histogram
__global__ __launch_bounds__(256) void deg_hist_k(
    const int* __restrict__ dst, const int* __restrict__ efeat,
    int* __restrict__ degs, int* __restrict__ cnt)
{
  int e = blockIdx.x * 256 + threadIdx.x;
  if (e >= N_EDGESC) return;
  int d = dst[e];
  atomicAdd(&degs[d], 1);
  int base = d * 24;
#pragma unroll
  for (int c = 0; c < 3; ++c) {
    int v = efeat[e * 3 + c];
    atomicAdd(&cnt[base + c * 8 + v], 1);
  }
}

// ---------------------------------------------------------------- exclusive scan
__global__ __launch_bounds__(1024) void scan_k(
    const int* __restrict__ deg, int* __restrict__ row_start, int n)
{
  __shared__ int buf[1024];
  __shared__ int carry;
  int t = threadIdx.x;
  if (t == 0) carry = 0;
  __syncthreads();
  for (int base = 0; base < n; base += 8192) {
    int loc[8];
    int s = 0;
    int idx0 = base + t * 8;
#pragma unroll
    for (int i = 0; i < 8; ++i) {
      int v = (idx0 + i < n) ? deg[idx0 + i] : 0;
      loc[i] = v; s += v;
    }
    buf[t] = s;
    __syncthreads();
    for (int off = 1; off < 1024; off <<= 1) {
      int add = (t >= off) ? buf[t - off] : 0;
      __syncthreads();
      buf[t] += add;
      __syncthreads();
    }
    int excl = buf[t] - s;
    int run = carry + excl;
#pragma unroll
    for (int i = 0; i < 8; ++i) {
      if (idx0 + i < n) row_start[idx0 + i] = run;
      run += loc[i];
    }
    __syncthreads();
    if (t == 1023) carry += buf[1023];
    __syncthreads();
  }
  if (t == 0) row_start[n] = carry;
}

// ---------------------------------------------------------------- CSR scatter
__global__ __launch_bounds__(256) void scatter_k(
    const int* __restrict__ src, const int* __restrict__ dst,
    const int* __restrict__ row_start, int* __restrict__ fill,
    int* __restrict__ csr)
{
  int e = blockIdx.x * 256 + threadIdx.x;
  if (e >= N_EDGESC) return;
  int d = dst[e];
  int pos = row_start[d] + atomicAdd(&fill[d], 1);
  csr[pos] = src[e];
}

// ---------------------------------------------------------------- aggregation
__global__ __launch_bounds__(256) void aggregate_k(
    const float* __restrict__ h, const float* __restrict__ emb_l,
    const int* __restrict__ csr, const int* __restrict__ row_start,
    const int* __restrict__ cnt, float* __restrict__ x)
{
  __shared__ float semb[24 * EMBEDC];
  for (int i = threadIdx.x; i < 24 * EMBEDC; i += 256) semb[i] = emb_l[i];
  __syncthreads();
  int w = threadIdx.x >> 6, lane = threadIdx.x & 63;
  int n = blockIdx.x * 4 + w;
  if (n >= N_NODESC) return;
  float4 acc = ((const float4*)(h + (long)n * EMBEDC))[lane];
  int s0 = row_start[n], s1 = row_start[n + 1];
  int e = s0;
  for (; e + 4 <= s1; e += 4) {
    int i0 = csr[e], i1 = csr[e + 1], i2 = csr[e + 2], i3 = csr[e + 3];
    float4 v0 = ((const float4*)(h + (long)i0 * EMBEDC))[lane];
    float4 v1 = ((const float4*)(h + (long)i1 * EMBEDC))[lane];
    float4 v2 = ((const float4*)(h + (long)i2 * EMBEDC))[lane];
    float4 v3 = ((const float4*)(h + (long)i3 * EMBEDC))[lane];
    acc.x += v0.x + v1.x + v2.x + v3.x;
    acc.y += v0.y + v1.y + v2.y + v3.y;
    acc.z += v0.z + v1.z + v2.z + v3.z;
    acc.w += v0.w + v1.w + v2.w + v3.w;
  }
  for (; e < s1; ++e) {
    int i0 = csr[e];
    float4 v0 = ((const float4*)(h + (long)i0 * EMBEDC))[lane];
    acc.x += v0.x; acc.y += v0.y; acc.z += v0.z; acc.w += v0.w;
  }
  const int* cn = cnt + n * 24;
#pragma unroll
  for (int j = 0; j < 24; ++j) {
    int cj = cn[j];
    if (cj) {
      float fc = (float)cj;
      float4 ev = ((const float4*)(semb + j * EMBEDC))[lane];
      acc.x += fc * ev.x; acc.y += fc * ev.y;
      acc.z += fc * ev.z; acc.w += fc * ev.w;
    }
  }
  float inv = 1.0f / (float)(s1 - s0 + 1);
  float4 o;
  o.x = acc.x * inv; o.y = acc.y * inv; o.z = acc.z * inv; o.w = acc.w * inv;
  ((float4*)(x + (long)n * EMBEDC))[lane] = o;
}

// ---------------------------------------------------------------- GEMM
// Y = X @ W + b over padded rows (X pad rows are zero -> Y pad rows = b).
// Per-block column partial sums/sumsqs written to Pp (no atomics).
__global__ __launch_bounds__(256) void gemm_k(
    const float* __restrict__ X, const float* __restrict__ Wl,
    const float* __restrict__ bl, float* __restrict__ Y,
    float* __restrict__ Pp)
{
  __shared__ float xsT[16 * 132];
  __shared__ float wsh[16 * 144];
  int t = threadIdx.x;
  int bm = blockIdx.x, bn = blockIdx.y;
  int row0 = bm * 128, nc0 = bn * 128;
  int tm = t >> 4, tn = t & 15;
  float acc[8][8];
#pragma unroll
  for (int i = 0; i < 8; ++i)
#pragma unroll
    for (int j = 0; j < 8; ++j) acc[i][j] = 0.f;

  int ln0 = tn * 4;           // local cols 0..63
  int ln1 = 64 + tn * 4;      // local cols 64..127
  int p0 = ln0 + ((ln0 >> 5) << 2);
  int p1 = ln1 + ((ln1 >> 5) << 2);

  for (int kc = 0; kc < 256; kc += 16) {
#pragma unroll
    for (int q = 0; q < 2; ++q) {
      int id = t + (q << 8);
      int kq = id & 3, m = id >> 2;
      float4 v = *(const float4*)(X + (long)(row0 + m) * 256 + kc + (kq << 2));
      xsT[(kq * 4 + 0) * 132 + m] = v.x;
      xsT[(kq * 4 + 1) * 132 + m] = v.y;
      xsT[(kq * 4 + 2) * 132 + m] = v.z;
      xsT[(kq * 4 + 3) * 132 + m] = v.w;
    }
#pragma unroll
    for (int q = 0; q < 2; ++q) {
      int id = t + (q << 8);
      int k = id >> 5, nf = (id & 31) << 2;
      float4 v = *(const float4*)(Wl + (long)(kc + k) * 256 + nc0 + nf);
      *(float4*)&wsh[k * 144 + nf + ((nf >> 5) << 2)] = v;
    }
    __syncthreads();
#pragma unroll
    for (int k = 0; k < 16; ++k) {
      float4 a0 = *(const float4*)&xsT[k * 132 + tm * 8];
      float4 a1 = *(const float4*)&xsT[k * 132 + tm * 8 + 4];
      float4 b0 = *(const float4*)&wsh[k * 144 + p0];
      float4 b1 = *(const float4*)&wsh[k * 144 + p1];
      float a[8] = {a0.x, a0.y, a0.z, a0.w, a1.x, a1.y, a1.z, a1.w};
      float bb[8] = {b0.x, b0.y, b0.z, b0.w, b1.x, b1.y, b1.z, b1.w};
#pragma unroll
      for (int i = 0; i < 8; ++i)
#pragma unroll
        for (int j = 0; j < 8; ++j) acc[i][j] += a[i] * bb[j];
    }
    __syncthreads();
  }

  // epilogue: bias + coalesced float4 stores + per-thread column partials
  float4 bj0 = *(const float4*)(bl + nc0 + ln0);
  float4 bj1 = *(const float4*)(bl + nc0 + ln1);
  float s[8], q2[8];
#pragma unroll
  for (int j = 0; j < 8; ++j) { s[j] = 0.f; q2[j] = 0.f; }
#pragma unroll
  for (int i = 0; i < 8; ++i) {
    int row = row0 + tm * 8 + i;
    float4 v0, v1;
    v0.x = acc[i][0] + bj0.x; v0.y = acc[i][1] + bj0.y;
    v0.z = acc[i][2] + bj0.z; v0.w = acc[i][3] + bj0.w;
    v1.x = acc[i][4] + bj1.x; v1.y = acc[i][5] + bj1.y;
    v1.z = acc[i][6] + bj1.z; v1.w = acc[i][7] + bj1.w;
    *(float4*)(Y + (long)row * 256 + nc0 + ln0) = v0;
    *(float4*)(Y + (long)row * 256 + nc0 + ln1) = v1;
    s[0] += v0.x; q2[0] += v0.x * v0.x;
    s[1] += v0.y; q2[1] += v0.y * v0.y;
    s[2] += v0.z; q2[2] += v0.z * v0.z;
    s[3] += v0.w; q2[3] += v0.w * v0.w;
    s[4] += v1.x; q2[4] += v1.x * v1.x;
    s[5] += v1.y; q2[5] += v1.y * v1.y;
    s[6] += v1.z; q2[6] += v1.z * v1.z;
    s[7] += v1.w; q2[7] += v1.w * v1.w;
  }
  // block-level reduce across the 16 tm groups via LDS (reuse tiles)
#pragma unroll
  for (int j = 0; j < 4; ++j) {
    xsT[tm * 132 + ln0 + j] = s[j];
    xsT[tm * 132 + ln1 + j] = s[4 + j];
    wsh[tm * 144 + ln0 + j] = q2[j];
    wsh[tm * 144 + ln1 + j] = q2[4 + j];
  }
  __syncthreads();
  if (t < 128) {
    float ssum = 0.f, qsum = 0.f;
#pragma unroll
    for (int g = 0; g < 16; ++g) {
      ssum += xsT[g * 132 + t];
      qsum += wsh[g * 144 + t];
    }
    float* p = Pp + (bm * 2 + bn) * 256;
    p[t] = ssum;
    p[128 + t] = qsum;
  }
}

// ------------------------------------------- BN stats reduce + finalize (1 block)
__global__ __launch_bounds__(256) void stats_finalize_k(
    const float* __restrict__ Pp, const float* __restrict__ bl,
    const float* __restrict__ gamma, const float* __restrict__ beta,
    float* __restrict__ scale, float* __restrict__ shiftv)
{
  int c = threadIdx.x;
  int half = c >> 7, cl = c & 127;
  float s = 0.f, s2 = 0.f;
  for (int bm = 0; bm < MTILES; ++bm) {
    const float* p = Pp + (bm * 2 + half) * 256;
    s += p[cl];
    s2 += p[128 + cl];
  }
  float bc = bl[c];
  // remove deterministic pad-row contribution (176 rows, each == b[c])
  s -= (float)(N_PAD - N_NODESC) * bc;
  s2 -= (float)(N_PAD - N_NODESC) * bc * bc;
  const float invN = 1.0f / (float)N_NODESC;
  float mu = s * invN;
  float var = s2 * invN - mu * mu;
  float rs = rsqrtf(var + 1e-5f);
  float sc = gamma[c] * rs;
  scale[c] = sc;
  shiftv[c] = beta[c] - mu * sc;
}

// ---------------------------------------------------------------- BN apply + relu
__global__ __launch_bounds__(256) void bn_relu_k(
    float* __restrict__ y, const float* __restrict__ scale,
    const float* __restrict__ shiftv)
{
  int i = blockIdx.x * 256 + threadIdx.x;  // float4 index over 50000 real rows
  int d = i & 63;
  float4 v = ((float4*)y)[i];
  float4 sc = ((const float4*)scale)[d];
  float4 sh = ((const float4*)shiftv)[d];
  v.x = fmaxf(0.f, v.x * sc.x + sh.x);
  v.y = fmaxf(0.f, v.y * sc.y + sh.y);
  v.z = fmaxf(0.f, v.z * sc.z + sh.z);
  v.w = fmaxf(0.f, v.w * sc.w + sh.w);
  ((float4*)y)[i] = v;
}

// ---------------------------------------------------------------- mean pooling
__device__ __forceinline__ int lower_bound_g(const int* gid, int n, int g)
{
  int lo = 0, hi = n;
  while (lo < hi) {
    int mid = (lo + hi) >> 1;
    if (gid[mid] < g) lo = mid + 1; else hi = mid;
  }
  return lo;
}

__global__ __launch_bounds__(256) void pool_k(
    const float* __restrict__ h, const int* __restrict__ gid,
    float* __restrict__ gpool)
{
  int g = blockIdx.x;
  int lo = lower_bound_g(gid, N_NODESC, g);
  int hi = lower_bound_g(gid, N_NODESC, g + 1);
  int c = hi - lo;
  float inv = 1.0f / (float)(c > 0 ? c : 1);
  int d = threadIdx.x;
  float acc = 0.f;
  for (int r = lo; r < hi; ++r) acc += h[(long)r * EMBEDC + d];
  gpool[g * EMBEDC + d] = acc * inv;
}

// ---------------------------------------------------------------- final proj
__global__ __launch_bounds__(128) void final_k(
    const float* __restrict__ gpool, const float* __restrict__ Wp,
    const float* __restrict__ bp, float* __restrict__ out)
{
  __shared__ float gr[256];
  int g = blockIdx.x, t = threadIdx.x;
  gr[t] = gpool[g * 256 + t];
  gr[t + 128] = gpool[g * 256 + t + 128];
  __syncthreads();
  float acc = bp[t];
#pragma unroll 8
  for (int k = 0; k < 256; ++k) acc += gr[k] * Wp[k * 128 + t];
  out[g * 128 + t] = acc;
}

// ---------------------------------------------------------------- launcher
extern "C" void kernel_launch(void* const* d_in, const int* in_sizes, int n_in,
                              void* d_out, int out_size, void* d_ws, size_t ws_size,
                              hipStream_t stream)
{
  (void)in_sizes; (void)n_in; (void)out_size; (void)ws_size;
  const int* nfeat = (const int*)d_in[0];
  const int* efeat = (const int*)d_in[1];
  const int* src = (const int*)d_in[2];
  const int* dst = (const int*)d_in[3];
  const int* gid = (const int*)d_in[4];
  const float* atom_emb = (const float*)d_in[5];
  const float* edge_emb = (const float*)d_in[6];
  const float* W = (const float*)d_in[7];
  const float* b = (const float*)d_in[8];
  const float* gamma = (const float*)d_in[9];
  const float* beta = (const float*)d_in[10];
  const float* Wp = (const float*)d_in[11];
  const float* bp = (const float*)d_in[12];
  float* out = (float*)d_out;

  char* ws = (char*)d_ws;
  float* A = (float*)ws; ws += (size_t)N_PAD * 1024;   // h / y (aliased)
  float* X = (float*)ws; ws += (size_t)N_PAD * 1024;   // aggregate output
  int* csr = (int*)ws; ws += 3200000;
  int* row_start = (int*)ws; ws += 200064;
  int* degs_i = (int*)ws; ws += 200064;
  int* fill = (int*)ws; ws += 200064;
  int* cnt = (int*)ws; ws += 4800000;
  float* Pp = (float*)ws; ws += MTILES * 2 * 256 * 4;  // per-block BN partials
  float* scale = (float*)ws; ws += 1024;
  float* shiftv = (float*)ws; ws += 1024;
  float* gpool = (float*)ws; ws += 131072;

  hipMemsetAsync(degs_i, 0, 200000, stream);
  hipMemsetAsync(fill, 0, 200000, stream);
  hipMemsetAsync(cnt, 0, 4800000, stream);
  // zero X pad rows (50000..50175) so GEMM pad output is exactly b[c]
  hipMemsetAsync(X + (size_t)N_NODESC * 256, 0,
                 (size_t)(N_PAD - N_NODESC) * 1024, stream);

  atom_encode_k<<<12500, 256, 0, stream>>>(nfeat, atom_emb, A);
  deg_hist_k<<<3125, 256, 0, stream>>>(dst, efeat, degs_i, cnt);
  scan_k<<<1, 1024, 0, stream>>>(degs_i, row_start, N_NODESC);
  scatter_k<<<3125, 256, 0, stream>>>(src, dst, row_start, fill, csr);

  for (int l = 0; l < 5; ++l) {
    aggregate_k<<<12500, 256, 0, stream>>>(A, edge_emb + l * 6144, csr,
                                           row_start, cnt, X);
    gemm_k<<<dim3(MTILES, 2), 256, 0, stream>>>(X, W + l * 65536, b + l * 256,
                                                A, Pp);
    stats_finalize_k<<<1, 256, 0, stream>>>(Pp, b + l * 256, gamma + l * 256,
                                            beta + l * 256, scale, shiftv);
    bn_relu_k<<<12500, 256, 0, stream>>>(A, scale, shiftv);
  }

  pool_k<<<128, 256, 0, stream>>>(A, gid, gpool);
  final_k<<<128, 128, 0, stream>>>(gpool, Wp, bp, out);
}

// Round 4
// 1236.802 us; speedup vs baseline: 7.6237x; 1.4052x over previous
//
#include <hip/hip_runtime.h>

#define N_NODESC 50000
#define N_PAD 50176          // 392 * 128
#define N_EDGESC 800000
#define N_GRAPHSC 128
#define EMBEDC 256
#define MTILES 392

typedef __attribute__((ext_vector_type(8))) short sh8;
typedef __attribute__((ext_vector_type(4))) float fx4;

// bf16 helpers (RNE)
__device__ __forceinline__ unsigned short f2bf(float f) {
  unsigned int u = __float_as_uint(f);
  unsigned int r = (u + 0x7FFFu + ((u >> 16) & 1u)) >> 16;
  return (unsigned short)r;
}
__device__ __forceinline__ float bf2f(unsigned short b) {
  return __uint_as_float(((unsigned int)b) << 16);
}
__device__ __forceinline__ void acc4(const uint2 u, float* a) {
  a[0] += __uint_as_float(u.x << 16);
  a[1] += __uint_as_float(u.x & 0xFFFF0000u);
  a[2] += __uint_as_float(u.y << 16);
  a[3] += __uint_as_float(u.y & 0xFFFF0000u);
}

// ---------------------------------------------------------------- atom encoder
// bf16 h interleaved in Y: row r = ushorts [r*512, r*512+256) == first 512B of Y row r
__global__ __launch_bounds__(256) void atom_encode_k(
    const int* __restrict__ nfeat, const float* __restrict__ atom_emb,
    unsigned short* __restrict__ hbu)
{
  int w = threadIdx.x >> 6, lane = threadIdx.x & 63;
  int n = blockIdx.x * 4 + w;
  if (n >= N_NODESC) return;
  const int* nf = nfeat + n * 9;
  float ax = 0.f, ay = 0.f, az = 0.f, aw = 0.f;
#pragma unroll
  for (int c = 0; c < 9; ++c) {
    int idx = nf[c];
    const float4* row = (const float4*)(atom_emb + (c * 128 + idx) * EMBEDC);
    float4 v = row[lane];
    ax += v.x; ay += v.y; az += v.z; aw += v.w;
  }
  ushort4 o;
  o.x = f2bf(ax); o.y = f2bf(ay); o.z = f2bf(az); o.w = f2bf(aw);
  *(ushort4*)(hbu + (long)n * 512 + lane * 4) = o;
}

// ------------------------------------------------- degree count + edge histogram
__global__ __launch_bounds__(256) void deg_hist_k(
    const int* __restrict__ dst, const int* __restrict__ efeat,
    int* __restrict__ degs, int* __restrict__ cnt)
{
  int e = blockIdx.x * 256 + threadIdx.x;
  if (e >= N_EDGESC) return;
  int d = dst[e];
  atomicAdd(&degs[d], 1);
  int base = d * 24;
#pragma unroll
  for (int c = 0; c < 3; ++c) {
    int v = efeat[e * 3 + c];
    atomicAdd(&cnt[base + c * 8 + v], 1);
  }
}

// ---------------------------------------------------------------- exclusive scan
__global__ __launch_bounds__(1024) void scan_k(
    const int* __restrict__ deg, int* __restrict__ row_start, int n)
{
  __shared__ int buf[1024];
  __shared__ int carry;
  int t = threadIdx.x;
  if (t == 0) carry = 0;
  __syncthreads();
  for (int base = 0; base < n; base += 8192) {
    int loc[8];
    int s = 0;
    int idx0 = base + t * 8;
#pragma unroll
    for (int i = 0; i < 8; ++i) {
      int v = (idx0 + i < n) ? deg[idx0 + i] : 0;
      loc[i] = v; s += v;
    }
    buf[t] = s;
    __syncthreads();
    for (int off = 1; off < 1024; off <<= 1) {
      int add = (t >= off) ? buf[t - off] : 0;
      __syncthreads();
      buf[t] += add;
      __syncthreads();
    }
    int excl = buf[t] - s;
    int run = carry + excl;
#pragma unroll
    for (int i = 0; i < 8; ++i) {
      if (idx0 + i < n) row_start[idx0 + i] = run;
      run += loc[i];
    }
    __syncthreads();
    if (t == 1023) carry += buf[1023];
    __syncthreads();
  }
  if (t == 0) row_start[n] = carry;
}

// ---------------------------------------------------------------- CSR scatter
__global__ __launch_bounds__(256) void scatter_k(
    const int* __restrict__ src, const int* __restrict__ dst,
    const int* __restrict__ row_start, int* __restrict__ fill,
    int* __restrict__ csr)
{
  int e = blockIdx.x * 256 + threadIdx.x;
  if (e >= N_EDGESC) return;
  int d = dst[e];
  int pos = row_start[d] + atomicAdd(&fill[d], 1);
  csr[pos] = src[e];
}

// ------------------------------------------------ W transpose + hi/lo bf16 split
__global__ __launch_bounds__(256) void wprep_k(
    const float* __restrict__ W, unsigned short* __restrict__ Wth,
    unsigned short* __restrict__ Wtl)
{
  int tid = blockIdx.x * 256 + threadIdx.x;     // 5*65536
  int l = tid >> 16, r = tid & 65535;
  int n = r >> 8, k = r & 255;
  float w = W[(long)l * 65536 + k * 256 + n];
  unsigned short hi = f2bf(w);
  Wth[tid] = hi;                                // tid == l*65536 + n*256 + k
  Wtl[tid] = f2bf(w - bf2f(hi));
}

// ---------------------------------------------------------------- aggregation
// x = (h[n] + sum_neigh h[src] + sum_j cnt[n][j]*emb_l[j]) / (deg+1), split hi/lo
__global__ __launch_bounds__(256) void aggregate_k(
    const unsigned short* hbu, const float* __restrict__ emb_l,
    const int* __restrict__ csr, const int* __restrict__ row_start,
    const int* __restrict__ cnt, unsigned short* __restrict__ Xh,
    unsigned short* __restrict__ Xl)
{
  __shared__ float semb[24 * EMBEDC];
  for (int i = threadIdx.x; i < 24 * EMBEDC; i += 256) semb[i] = emb_l[i];
  __syncthreads();
  int w = threadIdx.x >> 6, lane = threadIdx.x & 63;
  int n = blockIdx.x * 4 + w;
  if (n >= N_NODESC) return;
  float a[4] = {0.f, 0.f, 0.f, 0.f};
  acc4(*(const uint2*)(hbu + (long)n * 512 + lane * 4), a);  // self
  int s0 = row_start[n], s1 = row_start[n + 1];
  int e = s0;
  for (; e + 4 <= s1; e += 4) {
    int i0 = csr[e], i1 = csr[e + 1], i2 = csr[e + 2], i3 = csr[e + 3];
    uint2 u0 = *(const uint2*)(hbu + (long)i0 * 512 + lane * 4);
    uint2 u1 = *(const uint2*)(hbu + (long)i1 * 512 + lane * 4);
    uint2 u2 = *(const uint2*)(hbu + (long)i2 * 512 + lane * 4);
    uint2 u3 = *(const uint2*)(hbu + (long)i3 * 512 + lane * 4);
    acc4(u0, a); acc4(u1, a); acc4(u2, a); acc4(u3, a);
  }
  for (; e < s1; ++e) {
    uint2 u0 = *(const uint2*)(hbu + (long)csr[e] * 512 + lane * 4);
    acc4(u0, a);
  }
  const int* cn = cnt + n * 24;
#pragma unroll
  for (int j = 0; j < 24; ++j) {
    int cj = cn[j];
    if (cj) {
      float fc = (float)cj;
      float4 ev = *(const float4*)&semb[j * EMBEDC + lane * 4];
      a[0] += fc * ev.x; a[1] += fc * ev.y;
      a[2] += fc * ev.z; a[3] += fc * ev.w;
    }
  }
  float inv = 1.0f / (float)(s1 - s0 + 1);
  unsigned int ph[2], pl[2];
#pragma unroll
  for (int c = 0; c < 2; ++c) {
    float x0 = a[2 * c] * inv, x1 = a[2 * c + 1] * inv;
    unsigned short h0 = f2bf(x0), h1 = f2bf(x1);
    unsigned short l0 = f2bf(x0 - bf2f(h0)), l1 = f2bf(x1 - bf2f(h1));
    ph[c] = (unsigned int)h0 | ((unsigned int)h1 << 16);
    pl[c] = (unsigned int)l0 | ((unsigned int)l1 << 16);
  }
  long o = (long)n * 256 + lane * 4;
  *(uint2*)(Xh + o) = make_uint2(ph[0], ph[1]);
  *(uint2*)(Xl + o) = make_uint2(pl[0], pl[1]);
}

// ---------------------------------------------------------------- MFMA GEMM
// Y = (Xh+Xl) @ (Wh+Wl) + b ; per-block BN partials (no atomics)
__global__ __launch_bounds__(256) void gemm_k(
    const unsigned short* __restrict__ Xh, const unsigned short* __restrict__ Xl,
    const unsigned short* __restrict__ Bh, const unsigned short* __restrict__ Bl,
    const float* __restrict__ bl, float* __restrict__ Y, float* __restrict__ Pp)
{
  __shared__ unsigned short As_h[128 * 72];
  __shared__ unsigned short As_l[128 * 72];
  __shared__ unsigned short Bs_h[128 * 72];
  __shared__ unsigned short Bs_l[128 * 72];
  __shared__ float red_s[256];
  __shared__ float red_q[256];

  int t = threadIdx.x;
  int bm = blockIdx.x, bn = blockIdx.y;
  int row0 = bm * 128, nc0 = bn * 128;
  int w = t >> 6, l = t & 63;
  int wr = w >> 1, wc = w & 1;
  int lr = l & 15, lk = l >> 4;

  fx4 acc[4][4];
#pragma unroll
  for (int i = 0; i < 4; ++i)
#pragma unroll
    for (int j = 0; j < 4; ++j) acc[i][j] = (fx4){0.f, 0.f, 0.f, 0.f};

  for (int kc = 0; kc < 256; kc += 64) {
    __syncthreads();
#pragma unroll
    for (int q = 0; q < 4; ++q) {
      int id = q * 256 + t;
      int r = id >> 3, c8 = (id & 7) * 8;
      long gA = (long)(row0 + r) * 256 + kc + c8;
      long gB = (long)(nc0 + r) * 256 + kc + c8;
      *(uint4*)&As_h[r * 72 + c8] = *(const uint4*)(Xh + gA);
      *(uint4*)&As_l[r * 72 + c8] = *(const uint4*)(Xl + gA);
      *(uint4*)&Bs_h[r * 72 + c8] = *(const uint4*)(Bh + gB);
      *(uint4*)&Bs_l[r * 72 + c8] = *(const uint4*)(Bl + gB);
    }
    __syncthreads();
#pragma unroll
    for (int ks = 0; ks < 2; ++ks) {
      int ko = ks * 32 + lk * 8;
      sh8 ah[4], al[4], bh[4], bv[4];
#pragma unroll
      for (int f = 0; f < 4; ++f) {
        int ar = (wr * 64 + f * 16 + lr) * 72 + ko;
        int br = (wc * 64 + f * 16 + lr) * 72 + ko;
        ah[f] = *(const sh8*)&As_h[ar];
        al[f] = *(const sh8*)&As_l[ar];
        bh[f] = *(const sh8*)&Bs_h[br];
        bv[f] = *(const sh8*)&Bs_l[br];
      }
#pragma unroll
      for (int fm = 0; fm < 4; ++fm)
#pragma unroll
        for (int fn = 0; fn < 4; ++fn) {
          acc[fm][fn] = __builtin_amdgcn_mfma_f32_16x16x32_bf16(
              al[fm], bh[fn], acc[fm][fn], 0, 0, 0);
          acc[fm][fn] = __builtin_amdgcn_mfma_f32_16x16x32_bf16(
              ah[fm], bv[fn], acc[fm][fn], 0, 0, 0);
          acc[fm][fn] = __builtin_amdgcn_mfma_f32_16x16x32_bf16(
              ah[fm], bh[fn], acc[fm][fn], 0, 0, 0);
        }
    }
  }

  float bcol[4];
#pragma unroll
  for (int fn = 0; fn < 4; ++fn) bcol[fn] = bl[nc0 + wc * 64 + fn * 16 + lr];
  float sp[4] = {0.f, 0.f, 0.f, 0.f}, qp[4] = {0.f, 0.f, 0.f, 0.f};
#pragma unroll
  for (int fm = 0; fm < 4; ++fm)
#pragma unroll
    for (int fn = 0; fn < 4; ++fn) {
      int cl = wc * 64 + fn * 16 + lr;
#pragma unroll
      for (int j = 0; j < 4; ++j) {
        int rl = wr * 64 + fm * 16 + lk * 4 + j;
        float v = acc[fm][fn][j] + bcol[fn];
        Y[(long)(row0 + rl) * 256 + nc0 + cl] = v;
        sp[fn] += v; qp[fn] += v * v;
      }
    }
#pragma unroll
  for (int fn = 0; fn < 4; ++fn) {
    sp[fn] += __shfl_xor(sp[fn], 16);
    sp[fn] += __shfl_xor(sp[fn], 32);
    qp[fn] += __shfl_xor(qp[fn], 16);
    qp[fn] += __shfl_xor(qp[fn], 32);
  }
  if (lk == 0) {
#pragma unroll
    for (int fn = 0; fn < 4; ++fn) {
      red_s[w * 64 + fn * 16 + lr] = sp[fn];
      red_q[w * 64 + fn * 16 + lr] = qp[fn];
    }
  }
  __syncthreads();
  if (t < 128) {
    float s = red_s[t] + red_s[128 + t];
    float q = red_q[t] + red_q[128 + t];
    float* p = Pp + (bm * 2 + bn) * 256;
    p[t] = s;
    p[128 + t] = q;
  }
}

// ------------------------------------------- BN stats reduce + finalize (1 block)
__global__ __launch_bounds__(256) void stats_finalize_k(
    const float* __restrict__ Pp, const float* __restrict__ bl,
    const float* __restrict__ gamma, const float* __restrict__ beta,
    float* __restrict__ scale, float* __restrict__ shiftv)
{
  int c = threadIdx.x;
  int half = c >> 7, cl = c & 127;
  float s = 0.f, s2 = 0.f;
  for (int bm = 0; bm < MTILES; ++bm) {
    const float* p = Pp + (bm * 2 + half) * 256;
    s += p[cl];
    s2 += p[128 + cl];
  }
  float bc = bl[c];
  s -= (float)(N_PAD - N_NODESC) * bc;
  s2 -= (float)(N_PAD - N_NODESC) * bc * bc;
  const float invN = 1.0f / (float)N_NODESC;
  float mu = s * invN;
  float var = s2 * invN - mu * mu;
  float rs = rsqrtf(var + 1e-5f);
  float sc = gamma[c] * rs;
  scale[c] = sc;
  shiftv[c] = beta[c] - mu * sc;
}

// ------------------------------------------ BN apply + relu, write bf16 h in-place
// hbu row r = first 512B of Y row r; each block owns 4 complete rows.
__global__ __launch_bounds__(256) void bn_relu_k(
    const float* y, unsigned short* hbu,
    const float* __restrict__ scale, const float* __restrict__ shiftv)
{
  long i = (long)blockIdx.x * 256 + threadIdx.x;   // float4 index
  int d = (int)(i & 63);
  float4 v = ((const float4*)y)[i];
  float4 sc = ((const float4*)scale)[d];
  float4 sh = ((const float4*)shiftv)[d];
  float rx = fmaxf(0.f, v.x * sc.x + sh.x);
  float ry = fmaxf(0.f, v.y * sc.y + sh.y);
  float rz = fmaxf(0.f, v.z * sc.z + sh.z);
  float rw = fmaxf(0.f, v.w * sc.w + sh.w);
  __syncthreads();   // all reads of these 4 rows complete before aliasing writes
  int row = (int)(i >> 6);
  ushort4 o;
  o.x = f2bf(rx); o.y = f2bf(ry); o.z = f2bf(rz); o.w = f2bf(rw);
  *(ushort4*)(hbu + (long)row * 512 + d * 4) = o;
}

// ---------------------------------------------------------------- mean pooling
__device__ __forceinline__ int lower_bound_g(const int* gid, int n, int g)
{
  int lo = 0, hi = n;
  while (lo < hi) {
    int mid = (lo + hi) >> 1;
    if (gid[mid] < g) lo = mid + 1; else hi = mid;
  }
  return lo;
}

__global__ __launch_bounds__(256) void pool_k(
    const unsigned short* __restrict__ hbu, const int* __restrict__ gid,
    float* __restrict__ gpool)
{
  int g = blockIdx.x;
  int lo = lower_bound_g(gid, N_NODESC, g);
  int hi = lower_bound_g(gid, N_NODESC, g + 1);
  int c = hi - lo;
  float inv = 1.0f / (float)(c > 0 ? c : 1);
  int d = threadIdx.x;
  float acc = 0.f;
  for (int r = lo; r < hi; ++r) acc += bf2f(hbu[(long)r * 512 + d]);
  gpool[g * EMBEDC + d] = acc * inv;
}

// ---------------------------------------------------------------- final proj
__global__ __launch_bounds__(128) void final_k(
    const float* __restrict__ gpool, const float* __restrict__ Wp,
    const float* __restrict__ bp, float* __restrict__ out)
{
  __shared__ float gr[256];
  int g = blockIdx.x, t = threadIdx.x;
  gr[t] = gpool[g * 256 + t];
  gr[t + 128] = gpool[g * 256 + t + 128];
  __syncthreads();
  float acc = bp[t];
#pragma unroll 8
  for (int k = 0; k < 256; ++k) acc += gr[k] * Wp[k * 128 + t];
  out[g * 128 + t] = acc;
}

// ---------------------------------------------------------------- launcher
extern "C" void kernel_launch(void* const* d_in, const int* in_sizes, int n_in,
                              void* d_out, int out_size, void* d_ws, size_t ws_size,
                              hipStream_t stream)
{
  (void)in_sizes; (void)n_in; (void)out_size; (void)ws_size;
  const int* nfeat = (const int*)d_in[0];
  const int* efeat = (const int*)d_in[1];
  const int* src = (const int*)d_in[2];
  const int* dst = (const int*)d_in[3];
  const int* gid = (const int*)d_in[4];
  const float* atom_emb = (const float*)d_in[5];
  const float* edge_emb = (const float*)d_in[6];
  const float* W = (const float*)d_in[7];
  const float* b = (const float*)d_in[8];
  const float* gamma = (const float*)d_in[9];
  const float* beta = (const float*)d_in[10];
  const float* Wp = (const float*)d_in[11];
  const float* bp = (const float*)d_in[12];
  float* out = (float*)d_out;

  char* ws = (char*)d_ws;
  float* Y = (float*)ws; ws += (size_t)N_PAD * 1024;   // fp32 Y (+ bf16 h in first 512B/row)
  unsigned short* Xh = (unsigned short*)ws; ws += (size_t)N_PAD * 512;
  unsigned short* Xl = (unsigned short*)ws; ws += (size_t)N_PAD * 512;
  unsigned short* Wth = (unsigned short*)ws; ws += 5 * 65536 * 2;
  unsigned short* Wtl = (unsigned short*)ws; ws += 5 * 65536 * 2;
  int* csr = (int*)ws; ws += 3200000;
  int* row_start = (int*)ws; ws += 200064;
  int* degs_i = (int*)ws; ws += 200064;
  int* fill = (int*)ws; ws += 200064;
  int* cnt = (int*)ws; ws += 4800000;
  float* Pp = (float*)ws; ws += MTILES * 2 * 256 * 4;
  float* scale = (float*)ws; ws += 1024;
  float* shiftv = (float*)ws; ws += 1024;
  float* gpool = (float*)ws; ws += 131072;

  unsigned short* hbu = (unsigned short*)Y;

  hipMemsetAsync(degs_i, 0, 200000, stream);
  hipMemsetAsync(fill, 0, 200000, stream);
  hipMemsetAsync(cnt, 0, 4800000, stream);
  hipMemsetAsync(Xh + (size_t)N_NODESC * 256, 0, (size_t)(N_PAD - N_NODESC) * 512, stream);
  hipMemsetAsync(Xl + (size_t)N_NODESC * 256, 0, (size_t)(N_PAD - N_NODESC) * 512, stream);

  wprep_k<<<1280, 256, 0, stream>>>(W, Wth, Wtl);
  atom_encode_k<<<12500, 256, 0, stream>>>(nfeat, atom_emb, hbu);
  deg_hist_k<<<3125, 256, 0, stream>>>(dst, efeat, degs_i, cnt);
  scan_k<<<1, 1024, 0, stream>>>(degs_i, row_start, N_NODESC);
  scatter_k<<<3125, 256, 0, stream>>>(src, dst, row_start, fill, csr);

  for (int l = 0; l < 5; ++l) {
    aggregate_k<<<12500, 256, 0, stream>>>(hbu, edge_emb + l * 6144, csr,
                                           row_start, cnt, Xh, Xl);
    gemm_k<<<dim3(MTILES, 2), 256, 0, stream>>>(Xh, Xl, Wth + l * 65536,
                                                Wtl + l * 65536, b + l * 256,
                                                Y, Pp);
    stats_finalize_k<<<1, 256, 0, stream>>>(Pp, b + l * 256, gamma + l * 256,
                                            beta + l * 256, scale, shiftv);
    bn_relu_k<<<12500, 256, 0, stream>>>(Y, hbu, scale, shiftv);
  }

  pool_k<<<128, 256, 0, stream>>>(hbu, gid, gpool);
  final_k<<<128, 128, 0, stream>>>(gpool, Wp, bp, out);
}

// Round 5
// 1066.463 us; speedup vs baseline: 8.8414x; 1.1597x over previous
//
#include <hip/hip_runtime.h>

#define N_NODESC 50000
#define N_PAD 50176          // 392 * 128
#define N_EDGESC 800000
#define N_GRAPHSC 128
#define EMBEDC 256
#define MTILES 392

typedef __attribute__((ext_vector_type(8))) _Float16 hf8;
typedef __attribute__((ext_vector_type(4))) float fx4;

__device__ __forceinline__ float h2f(unsigned short u) {
  _Float16 h = *(_Float16*)&u;
  return (float)h;
}
__device__ __forceinline__ unsigned short f2h(float f) {
  _Float16 h = (_Float16)f;
  return *(unsigned short*)&h;
}

// ---------------------------------------------------------------- atom encoder
__global__ __launch_bounds__(256) void atom_encode_k(
    const int* __restrict__ nfeat, const float* __restrict__ atom_emb,
    unsigned short* __restrict__ h16)
{
  int w = threadIdx.x >> 6, lane = threadIdx.x & 63;
  int n = blockIdx.x * 4 + w;
  if (n >= N_NODESC) return;
  const int* nf = nfeat + n * 9;
  float ax = 0.f, ay = 0.f, az = 0.f, aw = 0.f;
#pragma unroll
  for (int c = 0; c < 9; ++c) {
    int idx = nf[c];
    const float4* row = (const float4*)(atom_emb + (c * 128 + idx) * EMBEDC);
    float4 v = row[lane];
    ax += v.x; ay += v.y; az += v.z; aw += v.w;
  }
  ushort4 o;
  o.x = f2h(ax); o.y = f2h(ay); o.z = f2h(az); o.w = f2h(aw);
  *(ushort4*)(h16 + (long)n * 256 + lane * 4) = o;
}

// ---------------------------------------------------------------- degree count
__global__ __launch_bounds__(256) void deg_k(
    const int* __restrict__ dst, int* __restrict__ degs)
{
  int e = blockIdx.x * 256 + threadIdx.x;
  if (e >= N_EDGESC) return;
  atomicAdd(&degs[dst[e]], 1);
}

// ---------------------------------------------------------------- exclusive scan
__global__ __launch_bounds__(1024) void scan_k(
    const int* __restrict__ deg, int* __restrict__ row_start, int n)
{
  __shared__ int buf[1024];
  __shared__ int carry;
  int t = threadIdx.x;
  if (t == 0) carry = 0;
  __syncthreads();
  for (int base = 0; base < n; base += 8192) {
    int loc[8];
    int s = 0;
    int idx0 = base + t * 8;
#pragma unroll
    for (int i = 0; i < 8; ++i) {
      int v = (idx0 + i < n) ? deg[idx0 + i] : 0;
      loc[i] = v; s += v;
    }
    buf[t] = s;
    __syncthreads();
    for (int off = 1; off < 1024; off <<= 1) {
      int add = (t >= off) ? buf[t - off] : 0;
      __syncthreads();
      buf[t] += add;
      __syncthreads();
    }
    int excl = buf[t] - s;
    int run = carry + excl;
#pragma unroll
    for (int i = 0; i < 8; ++i) {
      if (idx0 + i < n) row_start[idx0 + i] = run;
      run += loc[i];
    }
    __syncthreads();
    if (t == 1023) carry += buf[1023];
    __syncthreads();
  }
  if (t == 0) row_start[n] = carry;
}

// ---------------------------------------------------------------- CSR scatter
__global__ __launch_bounds__(256) void scatter_k(
    const int* __restrict__ src, const int* __restrict__ dst,
    const int* __restrict__ row_start, int* __restrict__ fill,
    int2* __restrict__ csr2)
{
  int e = blockIdx.x * 256 + threadIdx.x;
  if (e >= N_EDGESC) return;
  int d = dst[e];
  int pos = row_start[d] + atomicAdd(&fill[d], 1);
  csr2[pos] = make_int2(src[e], e);
}

// ------------------------------------------ per-node edge-feature histogram
__global__ __launch_bounds__(256) void cnt_k(
    const int2* __restrict__ csr2, const int* __restrict__ row_start,
    const int* __restrict__ efeat, int* __restrict__ cnt)
{
  __shared__ int lc[256 * 25];
  int t = threadIdx.x;
  int n = blockIdx.x * 256 + t;
  int base = t * 25;
#pragma unroll
  for (int j = 0; j < 24; ++j) lc[base + j] = 0;
  if (n >= N_NODESC) return;
  int s0 = row_start[n], s1 = row_start[n + 1];
  for (int e = s0; e < s1; ++e) {
    int eid = csr2[e].y;
    int v0 = efeat[eid * 3 + 0];
    int v1 = efeat[eid * 3 + 1];
    int v2 = efeat[eid * 3 + 2];
    lc[base + v0]++;
    lc[base + 8 + v1]++;
    lc[base + 16 + v2]++;
  }
#pragma unroll
  for (int j = 0; j < 24; ++j) cnt[n * 24 + j] = lc[base + j];
}

// ------------------------------------------------ W transpose + fp16 convert
__global__ __launch_bounds__(256) void wprep_k(
    const float* __restrict__ W, unsigned short* __restrict__ Wt)
{
  int tid = blockIdx.x * 256 + threadIdx.x;     // 5*65536
  int l = tid >> 16, r = tid & 65535;
  int n = r >> 8, k = r & 255;
  float w = W[(long)l * 65536 + k * 256 + n];
  Wt[tid] = f2h(w);                             // tid == l*65536 + n*256 + k
}

// ---------------------------------------------------------------- aggregation
// x = (h[n] + sum_neigh h[src] + sum_j cnt[n][j]*emb_l[j]) / (deg+1), fp16 out
__global__ __launch_bounds__(256) void aggregate_k(
    const unsigned short* __restrict__ h16, const float* __restrict__ emb_l,
    const int2* __restrict__ csr2, const int* __restrict__ row_start,
    const int* __restrict__ cnt, unsigned short* __restrict__ X16)
{
  __shared__ float semb[24 * EMBEDC];
  for (int i = threadIdx.x; i < 24 * EMBEDC; i += 256) semb[i] = emb_l[i];
  __syncthreads();
  int w = threadIdx.x >> 6, lane = threadIdx.x & 63;
  int n = blockIdx.x * 4 + w;
  if (n >= N_NODESC) return;
  float a0 = 0.f, a1 = 0.f, a2 = 0.f, a3 = 0.f;
  {
    ushort4 u = *(const ushort4*)(h16 + (long)n * 256 + lane * 4);
    a0 += h2f(u.x); a1 += h2f(u.y); a2 += h2f(u.z); a3 += h2f(u.w);
  }
  int s0 = row_start[n], s1 = row_start[n + 1];
  int e = s0;
  for (; e + 4 <= s1; e += 4) {
    int i0 = csr2[e].x, i1 = csr2[e + 1].x, i2 = csr2[e + 2].x, i3 = csr2[e + 3].x;
    ushort4 u0 = *(const ushort4*)(h16 + (long)i0 * 256 + lane * 4);
    ushort4 u1 = *(const ushort4*)(h16 + (long)i1 * 256 + lane * 4);
    ushort4 u2 = *(const ushort4*)(h16 + (long)i2 * 256 + lane * 4);
    ushort4 u3 = *(const ushort4*)(h16 + (long)i3 * 256 + lane * 4);
    a0 += h2f(u0.x) + h2f(u1.x) + h2f(u2.x) + h2f(u3.x);
    a1 += h2f(u0.y) + h2f(u1.y) + h2f(u2.y) + h2f(u3.y);
    a2 += h2f(u0.z) + h2f(u1.z) + h2f(u2.z) + h2f(u3.z);
    a3 += h2f(u0.w) + h2f(u1.w) + h2f(u2.w) + h2f(u3.w);
  }
  for (; e < s1; ++e) {
    ushort4 u = *(const ushort4*)(h16 + (long)csr2[e].x * 256 + lane * 4);
    a0 += h2f(u.x); a1 += h2f(u.y); a2 += h2f(u.z); a3 += h2f(u.w);
  }
  const int* cn = cnt + n * 24;
#pragma unroll
  for (int j = 0; j < 24; ++j) {
    int cj = cn[j];
    if (cj) {
      float fc = (float)cj;
      float4 ev = *(const float4*)&semb[j * EMBEDC + lane * 4];
      a0 += fc * ev.x; a1 += fc * ev.y;
      a2 += fc * ev.z; a3 += fc * ev.w;
    }
  }
  float inv = 1.0f / (float)(s1 - s0 + 1);
  ushort4 o;
  o.x = f2h(a0 * inv); o.y = f2h(a1 * inv);
  o.z = f2h(a2 * inv); o.w = f2h(a3 * inv);
  *(ushort4*)(X16 + (long)n * 256 + lane * 4) = o;
}

// ---------------------------------------------------------------- MFMA GEMM fp16
// Y16 = fp16(X @ W + b) ; per-block BN partials from fp32 accs (no atomics)
__global__ __launch_bounds__(256) void gemm_k(
    const unsigned short* __restrict__ X16, const unsigned short* __restrict__ Bt,
    const float* __restrict__ bl, unsigned short* __restrict__ Y16,
    float* __restrict__ Pp)
{
  __shared__ unsigned short As[128 * 72];
  __shared__ unsigned short Bs[128 * 72];
  __shared__ float red_s[256];
  __shared__ float red_q[256];

  int t = threadIdx.x;
  int bm = blockIdx.x, bn = blockIdx.y;
  int row0 = bm * 128, nc0 = bn * 128;
  int w = t >> 6, l = t & 63;
  int wr = w >> 1, wc = w & 1;
  int lr = l & 15, lk = l >> 4;

  fx4 acc[4][4];
#pragma unroll
  for (int i = 0; i < 4; ++i)
#pragma unroll
    for (int j = 0; j < 4; ++j) acc[i][j] = (fx4){0.f, 0.f, 0.f, 0.f};

  for (int kc = 0; kc < 256; kc += 64) {
    __syncthreads();
#pragma unroll
    for (int q = 0; q < 2; ++q) {
      int id = q * 256 + t;
      int r = id >> 2, c8 = (id & 3) * 16;
      long gA = (long)(row0 + r) * 256 + kc + c8;
      long gB = (long)(nc0 + r) * 256 + kc + c8;
      *(uint4*)&As[r * 72 + c8] = *(const uint4*)(X16 + gA);
      *(uint4*)&As[r * 72 + c8 + 8] = *(const uint4*)(X16 + gA + 8);
      *(uint4*)&Bs[r * 72 + c8] = *(const uint4*)(Bt + gB);
      *(uint4*)&Bs[r * 72 + c8 + 8] = *(const uint4*)(Bt + gB + 8);
    }
    __syncthreads();
#pragma unroll
    for (int ks = 0; ks < 2; ++ks) {
      int ko = ks * 32 + lk * 8;
      hf8 af[4], bf[4];
#pragma unroll
      for (int f = 0; f < 4; ++f) {
        af[f] = *(const hf8*)&As[(wr * 64 + f * 16 + lr) * 72 + ko];
        bf[f] = *(const hf8*)&Bs[(wc * 64 + f * 16 + lr) * 72 + ko];
      }
#pragma unroll
      for (int fm = 0; fm < 4; ++fm)
#pragma unroll
        for (int fn = 0; fn < 4; ++fn)
          acc[fm][fn] = __builtin_amdgcn_mfma_f32_16x16x32_f16(
              af[fm], bf[fn], acc[fm][fn], 0, 0, 0);
    }
  }

  float bcol[4];
#pragma unroll
  for (int fn = 0; fn < 4; ++fn) bcol[fn] = bl[nc0 + wc * 64 + fn * 16 + lr];
  float sp[4] = {0.f, 0.f, 0.f, 0.f}, qp[4] = {0.f, 0.f, 0.f, 0.f};
#pragma unroll
  for (int fm = 0; fm < 4; ++fm)
#pragma unroll
    for (int fn = 0; fn < 4; ++fn) {
      int cl = wc * 64 + fn * 16 + lr;
#pragma unroll
      for (int j = 0; j < 4; ++j) {
        int rl = wr * 64 + fm * 16 + lk * 4 + j;
        float v = acc[fm][fn][j] + bcol[fn];
        Y16[(long)(row0 + rl) * 256 + nc0 + cl] = f2h(v);
        sp[fn] += v; qp[fn] += v * v;
      }
    }
#pragma unroll
  for (int fn = 0; fn < 4; ++fn) {
    sp[fn] += __shfl_xor(sp[fn], 16);
    sp[fn] += __shfl_xor(sp[fn], 32);
    qp[fn] += __shfl_xor(qp[fn], 16);
    qp[fn] += __shfl_xor(qp[fn], 32);
  }
  if (lk == 0) {
#pragma unroll
    for (int fn = 0; fn < 4; ++fn) {
      red_s[w * 64 + fn * 16 + lr] = sp[fn];
      red_q[w * 64 + fn * 16 + lr] = qp[fn];
    }
  }
  __syncthreads();
  if (t < 128) {
    float s = red_s[t] + red_s[128 + t];
    float q = red_q[t] + red_q[128 + t];
    float* p = Pp + (bm * 2 + bn) * 256;
    p[t] = s;
    p[128 + t] = q;
  }
}

// ------------------------------------------- BN stats reduce + finalize (1 block)
__global__ __launch_bounds__(256) void stats_finalize_k(
    const float* __restrict__ Pp, const float* __restrict__ bl,
    const float* __restrict__ gamma, const float* __restrict__ beta,
    float* __restrict__ scale, float* __restrict__ shiftv)
{
  int c = threadIdx.x;
  int half = c >> 7, cl = c & 127;
  float s = 0.f, s2 = 0.f;
  for (int bm = 0; bm < MTILES; ++bm) {
    const float* p = Pp + (bm * 2 + half) * 256;
    s += p[cl];
    s2 += p[128 + cl];
  }
  float bc = bl[c];
  s -= (float)(N_PAD - N_NODESC) * bc;
  s2 -= (float)(N_PAD - N_NODESC) * bc * bc;
  const float invN = 1.0f / (float)N_NODESC;
  float mu = s * invN;
  float var = s2 * invN - mu * mu;
  float rs = rsqrtf(var + 1e-5f);
  float sc = gamma[c] * rs;
  scale[c] = sc;
  shiftv[c] = beta[c] - mu * sc;
}

// ---------------------------------------------- BN apply + relu (fp16 in/out)
__global__ __launch_bounds__(256) void bn_relu_k(
    const unsigned short* __restrict__ Y16, unsigned short* __restrict__ h16,
    const float* __restrict__ scale, const float* __restrict__ shiftv)
{
  long i = (long)blockIdx.x * 256 + threadIdx.x;   // uint4 (8-half) index, 1.6M
  int cg = (int)(i & 31);
  long off = i * 8;
  ushort4 ua = *(const ushort4*)(Y16 + off);
  ushort4 ub = *(const ushort4*)(Y16 + off + 4);
  float4 sc0 = ((const float4*)scale)[cg * 2];
  float4 sc1 = ((const float4*)scale)[cg * 2 + 1];
  float4 sh0 = ((const float4*)shiftv)[cg * 2];
  float4 sh1 = ((const float4*)shiftv)[cg * 2 + 1];
  ushort4 oa, ob;
  oa.x = f2h(fmaxf(0.f, h2f(ua.x) * sc0.x + sh0.x));
  oa.y = f2h(fmaxf(0.f, h2f(ua.y) * sc0.y + sh0.y));
  oa.z = f2h(fmaxf(0.f, h2f(ua.z) * sc0.z + sh0.z));
  oa.w = f2h(fmaxf(0.f, h2f(ua.w) * sc0.w + sh0.w));
  ob.x = f2h(fmaxf(0.f, h2f(ub.x) * sc1.x + sh1.x));
  ob.y = f2h(fmaxf(0.f, h2f(ub.y) * sc1.y + sh1.y));
  ob.z = f2h(fmaxf(0.f, h2f(ub.z) * sc1.z + sh1.z));
  ob.w = f2h(fmaxf(0.f, h2f(ub.w) * sc1.w + sh1.w));
  *(ushort4*)(h16 + off) = oa;
  *(ushort4*)(h16 + off + 4) = ob;
}

// ---------------------------------------------------------------- mean pooling
__device__ __forceinline__ int lower_bound_g(const int* gid, int n, int g)
{
  int lo = 0, hi = n;
  while (lo < hi) {
    int mid = (lo + hi) >> 1;
    if (gid[mid] < g) lo = mid + 1; else hi = mid;
  }
  return lo;
}

__global__ __launch_bounds__(256) void pool_k(
    const unsigned short* __restrict__ h16, const int* __restrict__ gid,
    float* __restrict__ gpool)
{
  int g = blockIdx.x;
  int lo = lower_bound_g(gid, N_NODESC, g);
  int hi = lower_bound_g(gid, N_NODESC, g + 1);
  int c = hi - lo;
  float inv = 1.0f / (float)(c > 0 ? c : 1);
  int d = threadIdx.x;
  float acc = 0.f;
  for (int r = lo; r < hi; ++r) acc += h2f(h16[(long)r * 256 + d]);
  gpool[g * EMBEDC + d] = acc * inv;
}

// ---------------------------------------------------------------- final proj
__global__ __launch_bounds__(128) void final_k(
    const float* __restrict__ gpool, const float* __restrict__ Wp,
    const float* __restrict__ bp, float* __restrict__ out)
{
  __shared__ float gr[256];
  int g = blockIdx.x, t = threadIdx.x;
  gr[t] = gpool[g * 256 + t];
  gr[t + 128] = gpool[g * 256 + t + 128];
  __syncthreads();
  float acc = bp[t];
#pragma unroll 8
  for (int k = 0; k < 256; ++k) acc += gr[k] * Wp[k * 128 + t];
  out[g * 128 + t] = acc;
}

// ---------------------------------------------------------------- launcher
extern "C" void kernel_launch(void* const* d_in, const int* in_sizes, int n_in,
                              void* d_out, int out_size, void* d_ws, size_t ws_size,
                              hipStream_t stream)
{
  (void)in_sizes; (void)n_in; (void)out_size; (void)ws_size;
  const int* nfeat = (const int*)d_in[0];
  const int* efeat = (const int*)d_in[1];
  const int* src = (const int*)d_in[2];
  const int* dst = (const int*)d_in[3];
  const int* gid = (const int*)d_in[4];
  const float* atom_emb = (const float*)d_in[5];
  const float* edge_emb = (const float*)d_in[6];
  const float* W = (const float*)d_in[7];
  const float* b = (const float*)d_in[8];
  const float* gamma = (const float*)d_in[9];
  const float* beta = (const float*)d_in[10];
  const float* Wp = (const float*)d_in[11];
  const float* bp = (const float*)d_in[12];
  float* out = (float*)d_out;

  char* ws = (char*)d_ws;
  unsigned short* h16 = (unsigned short*)ws; ws += (size_t)N_PAD * 512;
  unsigned short* Y16 = (unsigned short*)ws; ws += (size_t)N_PAD * 512;
  unsigned short* X16 = (unsigned short*)ws; ws += (size_t)N_PAD * 512;
  unsigned short* Wt = (unsigned short*)ws; ws += 5 * 65536 * 2;
  int2* csr2 = (int2*)ws; ws += 6400000;
  int* row_start = (int*)ws; ws += 200064;
  int* degs_i = (int*)ws; ws += 200064;
  int* fill = (int*)ws; ws += 200064;
  int* cnt = (int*)ws; ws += 4800000;
  float* Pp = (float*)ws; ws += MTILES * 2 * 256 * 4;
  float* scale = (float*)ws; ws += 1024;
  float* shiftv = (float*)ws; ws += 1024;
  float* gpool = (float*)ws; ws += 131072;

  hipMemsetAsync(degs_i, 0, 200000, stream);
  hipMemsetAsync(fill, 0, 200000, stream);
  // zero X pad rows so GEMM pad output is exactly b[c]
  hipMemsetAsync(X16 + (size_t)N_NODESC * 256, 0,
                 (size_t)(N_PAD - N_NODESC) * 512, stream);

  wprep_k<<<1280, 256, 0, stream>>>(W, Wt);
  atom_encode_k<<<12500, 256, 0, stream>>>(nfeat, atom_emb, h16);
  deg_k<<<3125, 256, 0, stream>>>(dst, degs_i);
  scan_k<<<1, 1024, 0, stream>>>(degs_i, row_start, N_NODESC);
  scatter_k<<<3125, 256, 0, stream>>>(src, dst, row_start, fill, csr2);
  cnt_k<<<196, 256, 0, stream>>>(csr2, row_start, efeat, cnt);

  for (int l = 0; l < 5; ++l) {
    aggregate_k<<<12500, 256, 0, stream>>>(h16, edge_emb + l * 6144, csr2,
                                           row_start, cnt, X16);
    gemm_k<<<dim3(MTILES, 2), 256, 0, stream>>>(X16, Wt + l * 65536, b + l * 256,
                                                Y16, Pp);
    stats_finalize_k<<<1, 256, 0, stream>>>(Pp, b + l * 256, gamma + l * 256,
                                            beta + l * 256, scale, shiftv);
    bn_relu_k<<<6250, 256, 0, stream>>>(Y16, h16, scale, shiftv);
  }

  pool_k<<<128, 256, 0, stream>>>(h16, gid, gpool);
  final_k<<<128, 128, 0, stream>>>(gpool, Wp, bp, out);
}

// Round 6
// 953.751 us; speedup vs baseline: 9.8862x; 1.1182x over previous
//
#include <hip/hip_runtime.h>

#define N_NODESC 50000
#define N_PAD 50176          // 392 * 128
#define N_EDGESC 800000
#define N_GRAPHSC 128
#define EMBEDC 256
#define MTILES 392

typedef __attribute__((ext_vector_type(8))) _Float16 hf8;
typedef __attribute__((ext_vector_type(4))) float fx4;

__device__ __forceinline__ float h2f(unsigned short u) {
  _Float16 h = *(_Float16*)&u;
  return (float)h;
}
__device__ __forceinline__ unsigned short f2h(float f) {
  _Float16 h = (_Float16)f;
  return *(unsigned short*)&h;
}
__device__ __forceinline__ unsigned int packh2(float lo, float hi) {
  return (unsigned int)f2h(lo) | ((unsigned int)f2h(hi) << 16);
}
// accumulate 8 packed halves (uint4) into a[8], fp32
__device__ __forceinline__ void acc8h(const uint4 u, float* a) {
  a[0] += h2f((unsigned short)(u.x & 0xFFFF));
  a[1] += h2f((unsigned short)(u.x >> 16));
  a[2] += h2f((unsigned short)(u.y & 0xFFFF));
  a[3] += h2f((unsigned short)(u.y >> 16));
  a[4] += h2f((unsigned short)(u.z & 0xFFFF));
  a[5] += h2f((unsigned short)(u.z >> 16));
  a[6] += h2f((unsigned short)(u.w & 0xFFFF));
  a[7] += h2f((unsigned short)(u.w >> 16));
}

// ---------------------------------------------------------------- atom encoder
__global__ __launch_bounds__(256) void atom_encode_k(
    const int* __restrict__ nfeat, const float* __restrict__ atom_emb,
    unsigned short* __restrict__ h16)
{
  int w = threadIdx.x >> 6, lane = threadIdx.x & 63;
  int n = blockIdx.x * 4 + w;
  if (n >= N_NODESC) return;
  const int* nf = nfeat + n * 9;
  float ax = 0.f, ay = 0.f, az = 0.f, aw = 0.f;
#pragma unroll
  for (int c = 0; c < 9; ++c) {
    int idx = nf[c];
    const float4* row = (const float4*)(atom_emb + (c * 128 + idx) * EMBEDC);
    float4 v = row[lane];
    ax += v.x; ay += v.y; az += v.z; aw += v.w;
  }
  ushort4 o;
  o.x = f2h(ax); o.y = f2h(ay); o.z = f2h(az); o.w = f2h(aw);
  *(ushort4*)(h16 + (long)n * 256 + lane * 4) = o;
}

// ---------------------------------------------------------------- degree count
__global__ __launch_bounds__(256) void deg_k(
    const int* __restrict__ dst, int* __restrict__ degs)
{
  int e = blockIdx.x * 256 + threadIdx.x;
  if (e >= N_EDGESC) return;
  atomicAdd(&degs[dst[e]], 1);
}

// ---------------------------------------------------------------- exclusive scan
__global__ __launch_bounds__(1024) void scan_k(
    const int* __restrict__ deg, int* __restrict__ row_start, int n)
{
  __shared__ int buf[1024];
  __shared__ int carry;
  int t = threadIdx.x;
  if (t == 0) carry = 0;
  __syncthreads();
  for (int base = 0; base < n; base += 8192) {
    int loc[8];
    int s = 0;
    int idx0 = base + t * 8;
#pragma unroll
    for (int i = 0; i < 8; ++i) {
      int v = (idx0 + i < n) ? deg[idx0 + i] : 0;
      loc[i] = v; s += v;
    }
    buf[t] = s;
    __syncthreads();
    for (int off = 1; off < 1024; off <<= 1) {
      int add = (t >= off) ? buf[t - off] : 0;
      __syncthreads();
      buf[t] += add;
      __syncthreads();
    }
    int excl = buf[t] - s;
    int run = carry + excl;
#pragma unroll
    for (int i = 0; i < 8; ++i) {
      if (idx0 + i < n) row_start[idx0 + i] = run;
      run += loc[i];
    }
    __syncthreads();
    if (t == 1023) carry += buf[1023];
    __syncthreads();
  }
  if (t == 0) row_start[n] = carry;
}

// ---------------------------------------------------------------- CSR scatter
__global__ __launch_bounds__(256) void scatter_k(
    const int* __restrict__ src, const int* __restrict__ dst,
    const int* __restrict__ row_start, int* __restrict__ fill,
    int2* __restrict__ csr2)
{
  int e = blockIdx.x * 256 + threadIdx.x;
  if (e >= N_EDGESC) return;
  int d = dst[e];
  int pos = row_start[d] + atomicAdd(&fill[d], 1);
  csr2[pos] = make_int2(src[e], e);
}

// ------------------------------------------ per-node edge-feature histogram
__global__ __launch_bounds__(256) void cnt_k(
    const int2* __restrict__ csr2, const int* __restrict__ row_start,
    const int* __restrict__ efeat, int* __restrict__ cnt)
{
  __shared__ int lc[256 * 25];
  int t = threadIdx.x;
  int n = blockIdx.x * 256 + t;
  int base = t * 25;
#pragma unroll
  for (int j = 0; j < 24; ++j) lc[base + j] = 0;
  if (n >= N_NODESC) return;
  int s0 = row_start[n], s1 = row_start[n + 1];
  for (int e = s0; e < s1; ++e) {
    int eid = csr2[e].y;
    int v0 = efeat[eid * 3 + 0];
    int v1 = efeat[eid * 3 + 1];
    int v2 = efeat[eid * 3 + 2];
    lc[base + v0]++;
    lc[base + 8 + v1]++;
    lc[base + 16 + v2]++;
  }
#pragma unroll
  for (int j = 0; j < 24; ++j) cnt[n * 24 + j] = lc[base + j];
}

// ------------------------------------------------ W transpose + fp16 convert
__global__ __launch_bounds__(256) void wprep_k(
    const float* __restrict__ W, unsigned short* __restrict__ Wt)
{
  int tid = blockIdx.x * 256 + threadIdx.x;     // 5*65536
  int l = tid >> 16, r = tid & 65535;
  int n = r >> 8, k = r & 255;
  float w = W[(long)l * 65536 + k * 256 + n];
  Wt[tid] = f2h(w);                             // tid == l*65536 + n*256 + k
}

// ---------------------------------------------------------------- aggregation
// wave = 1 node; half-wave (32 lanes x 16B) = 1 full 512B row -> 2 edges/instr.
// x = (h[n] + sum_neigh h[src] + sum_j cnt[n][j]*emb_l[j]) / (deg+1), fp16 out
__global__ __launch_bounds__(256) void aggregate_k(
    const unsigned short* __restrict__ h16, const float* __restrict__ emb_l,
    const int2* __restrict__ csr2, const int* __restrict__ row_start,
    const int* __restrict__ cnt, unsigned short* __restrict__ X16)
{
  __shared__ float semb[24 * EMBEDC];
  for (int i = threadIdx.x; i < 24 * EMBEDC; i += 256) semb[i] = emb_l[i];
  __syncthreads();
  int w = threadIdx.x >> 6, lane = threadIdx.x & 63;
  int n = blockIdx.x * 4 + w;
  if (n >= N_NODESC) return;
  int half = lane >> 5;          // 0/1: which edge of the pair
  int c8 = (lane & 31) * 8;      // 8 columns per lane
  float a[8] = {0.f, 0.f, 0.f, 0.f, 0.f, 0.f, 0.f, 0.f};
  int s0 = row_start[n], s1 = row_start[n + 1];
  if (half == 0) {               // self row, once
    uint4 u = *(const uint4*)(h16 + (long)n * 256 + c8);
    acc8h(u, a);
  }
  int e = s0 + half;             // half 0: even offsets, half 1: odd offsets
  for (; e + 6 < s1; e += 8) {
    int i0 = csr2[e].x, i1 = csr2[e + 2].x, i2 = csr2[e + 4].x, i3 = csr2[e + 6].x;
    uint4 u0 = *(const uint4*)(h16 + (long)i0 * 256 + c8);
    uint4 u1 = *(const uint4*)(h16 + (long)i1 * 256 + c8);
    uint4 u2 = *(const uint4*)(h16 + (long)i2 * 256 + c8);
    uint4 u3 = *(const uint4*)(h16 + (long)i3 * 256 + c8);
    acc8h(u0, a); acc8h(u1, a); acc8h(u2, a); acc8h(u3, a);
  }
  for (; e < s1; e += 2) {
    uint4 u = *(const uint4*)(h16 + (long)csr2[e].x * 256 + c8);
    acc8h(u, a);
  }
  // combine the two halves (lanes l and l^32 hold the same columns)
#pragma unroll
  for (int k = 0; k < 8; ++k) a[k] += __shfl_xor(a[k], 32);
  const int* cn = cnt + n * 24;
#pragma unroll
  for (int j = 0; j < 24; ++j) {
    int cj = cn[j];
    if (cj) {
      float fc = (float)cj;
      float4 e0 = *(const float4*)&semb[j * EMBEDC + c8];
      float4 e1 = *(const float4*)&semb[j * EMBEDC + c8 + 4];
      a[0] += fc * e0.x; a[1] += fc * e0.y; a[2] += fc * e0.z; a[3] += fc * e0.w;
      a[4] += fc * e1.x; a[5] += fc * e1.y; a[6] += fc * e1.z; a[7] += fc * e1.w;
    }
  }
  if (half == 0) {
    float inv = 1.0f / (float)(s1 - s0 + 1);
    uint4 o;
    o.x = packh2(a[0] * inv, a[1] * inv);
    o.y = packh2(a[2] * inv, a[3] * inv);
    o.z = packh2(a[4] * inv, a[5] * inv);
    o.w = packh2(a[6] * inv, a[7] * inv);
    *(uint4*)(X16 + (long)n * 256 + c8) = o;
  }
}

// ---------------------------------------------------------------- MFMA GEMM fp16
// Y16 = fp16(X @ W + b) ; per-block BN partials from fp32 accs (no atomics)
__global__ __launch_bounds__(256) void gemm_k(
    const unsigned short* __restrict__ X16, const unsigned short* __restrict__ Bt,
    const float* __restrict__ bl, unsigned short* __restrict__ Y16,
    float* __restrict__ Pp)
{
  __shared__ unsigned short As[128 * 72];
  __shared__ unsigned short Bs[128 * 72];
  __shared__ float red_s[256];
  __shared__ float red_q[256];

  int t = threadIdx.x;
  int bm = blockIdx.x, bn = blockIdx.y;
  int row0 = bm * 128, nc0 = bn * 128;
  int w = t >> 6, l = t & 63;
  int wr = w >> 1, wc = w & 1;
  int lr = l & 15, lk = l >> 4;

  fx4 acc[4][4];
#pragma unroll
  for (int i = 0; i < 4; ++i)
#pragma unroll
    for (int j = 0; j < 4; ++j) acc[i][j] = (fx4){0.f, 0.f, 0.f, 0.f};

  for (int kc = 0; kc < 256; kc += 64) {
    __syncthreads();
#pragma unroll
    for (int q = 0; q < 2; ++q) {
      int id = q * 256 + t;
      int r = id >> 2, c8 = (id & 3) * 16;
      long gA = (long)(row0 + r) * 256 + kc + c8;
      long gB = (long)(nc0 + r) * 256 + kc + c8;
      *(uint4*)&As[r * 72 + c8] = *(const uint4*)(X16 + gA);
      *(uint4*)&As[r * 72 + c8 + 8] = *(const uint4*)(X16 + gA + 8);
      *(uint4*)&Bs[r * 72 + c8] = *(const uint4*)(Bt + gB);
      *(uint4*)&Bs[r * 72 + c8 + 8] = *(const uint4*)(Bt + gB + 8);
    }
    __syncthreads();
#pragma unroll
    for (int ks = 0; ks < 2; ++ks) {
      int ko = ks * 32 + lk * 8;
      hf8 af[4], bf[4];
#pragma unroll
      for (int f = 0; f < 4; ++f) {
        af[f] = *(const hf8*)&As[(wr * 64 + f * 16 + lr) * 72 + ko];
        bf[f] = *(const hf8*)&Bs[(wc * 64 + f * 16 + lr) * 72 + ko];
      }
#pragma unroll
      for (int fm = 0; fm < 4; ++fm)
#pragma unroll
        for (int fn = 0; fn < 4; ++fn)
          acc[fm][fn] = __builtin_amdgcn_mfma_f32_16x16x32_f16(
              af[fm], bf[fn], acc[fm][fn], 0, 0, 0);
    }
  }

  float bcol[4];
#pragma unroll
  for (int fn = 0; fn < 4; ++fn) bcol[fn] = bl[nc0 + wc * 64 + fn * 16 + lr];
  float sp[4] = {0.f, 0.f, 0.f, 0.f}, qp[4] = {0.f, 0.f, 0.f, 0.f};
#pragma unroll
  for (int fm = 0; fm < 4; ++fm)
#pragma unroll
    for (int fn = 0; fn < 4; ++fn) {
      int cl = wc * 64 + fn * 16 + lr;
#pragma unroll
      for (int j = 0; j < 4; ++j) {
        int rl = wr * 64 + fm * 16 + lk * 4 + j;
        float v = acc[fm][fn][j] + bcol[fn];
        Y16[(long)(row0 + rl) * 256 + nc0 + cl] = f2h(v);
        sp[fn] += v; qp[fn] += v * v;
      }
    }
#pragma unroll
  for (int fn = 0; fn < 4; ++fn) {
    sp[fn] += __shfl_xor(sp[fn], 16);
    sp[fn] += __shfl_xor(sp[fn], 32);
    qp[fn] += __shfl_xor(qp[fn], 16);
    qp[fn] += __shfl_xor(qp[fn], 32);
  }
  if (lk == 0) {
#pragma unroll
    for (int fn = 0; fn < 4; ++fn) {
      red_s[w * 64 + fn * 16 + lr] = sp[fn];
      red_q[w * 64 + fn * 16 + lr] = qp[fn];
    }
  }
  __syncthreads();
  if (t < 128) {
    float s = red_s[t] + red_s[128 + t];
    float q = red_q[t] + red_q[128 + t];
    float* p = Pp + (bm * 2 + bn) * 256;
    p[t] = s;
    p[128 + t] = q;
  }
}

// ------------------------------------------- BN stats reduce + finalize (1 block)
__global__ __launch_bounds__(256) void stats_finalize_k(
    const float* __restrict__ Pp, const float* __restrict__ bl,
    const float* __restrict__ gamma, const float* __restrict__ beta,
    float* __restrict__ scale, float* __restrict__ shiftv)
{
  int c = threadIdx.x;
  int half = c >> 7, cl = c & 127;
  float s = 0.f, s2 = 0.f;
  for (int bm = 0; bm < MTILES; ++bm) {
    const float* p = Pp + (bm * 2 + half) * 256;
    s += p[cl];
    s2 += p[128 + cl];
  }
  float bc = bl[c];
  s -= (float)(N_PAD - N_NODESC) * bc;
  s2 -= (float)(N_PAD - N_NODESC) * bc * bc;
  const float invN = 1.0f / (float)N_NODESC;
  float mu = s * invN;
  float var = s2 * invN - mu * mu;
  float rs = rsqrtf(var + 1e-5f);
  float sc = gamma[c] * rs;
  scale[c] = sc;
  shiftv[c] = beta[c] - mu * sc;
}

// ---------------------------------------------- BN apply + relu (fp16 in/out)
__global__ __launch_bounds__(256) void bn_relu_k(
    const unsigned short* __restrict__ Y16, unsigned short* __restrict__ h16,
    const float* __restrict__ scale, const float* __restrict__ shiftv)
{
  long i = (long)blockIdx.x * 256 + threadIdx.x;   // uint4 (8-half) index, 1.6M
  int cg = (int)(i & 31);
  long off = i * 8;
  ushort4 ua = *(const ushort4*)(Y16 + off);
  ushort4 ub = *(const ushort4*)(Y16 + off + 4);
  float4 sc0 = ((const float4*)scale)[cg * 2];
  float4 sc1 = ((const float4*)scale)[cg * 2 + 1];
  float4 sh0 = ((const float4*)shiftv)[cg * 2];
  float4 sh1 = ((const float4*)shiftv)[cg * 2 + 1];
  ushort4 oa, ob;
  oa.x = f2h(fmaxf(0.f, h2f(ua.x) * sc0.x + sh0.x));
  oa.y = f2h(fmaxf(0.f, h2f(ua.y) * sc0.y + sh0.y));
  oa.z = f2h(fmaxf(0.f, h2f(ua.z) * sc0.z + sh0.z));
  oa.w = f2h(fmaxf(0.f, h2f(ua.w) * sc0.w + sh0.w));
  ob.x = f2h(fmaxf(0.f, h2f(ub.x) * sc1.x + sh1.x));
  ob.y = f2h(fmaxf(0.f, h2f(ub.y) * sc1.y + sh1.y));
  ob.z = f2h(fmaxf(0.f, h2f(ub.z) * sc1.z + sh1.z));
  ob.w = f2h(fmaxf(0.f, h2f(ub.w) * sc1.w + sh1.w));
  *(ushort4*)(h16 + off) = oa;
  *(ushort4*)(h16 + off + 4) = ob;
}

// ---------------------------------------------------------------- mean pooling
__device__ __forceinline__ int lower_bound_g(const int* gid, int n, int g)
{
  int lo = 0, hi = n;
  while (lo < hi) {
    int mid = (lo + hi) >> 1;
    if (gid[mid] < g) lo = mid + 1; else hi = mid;
  }
  return lo;
}

// 1 block per graph, 8 waves stride rows, lane covers 4 cols; LDS reduce.
__global__ __launch_bounds__(512) void pool_k(
    const unsigned short* __restrict__ h16, const int* __restrict__ gid,
    float* __restrict__ gpool)
{
  __shared__ float red[8 * 256];
  int g = blockIdx.x;
  int lo = lower_bound_g(gid, N_NODESC, g);
  int hi = lower_bound_g(gid, N_NODESC, g + 1);
  int t = threadIdx.x;
  int w = t >> 6, lane = t & 63;
  int col = lane * 4;
  float a0 = 0.f, a1 = 0.f, a2 = 0.f, a3 = 0.f;
  for (int r = lo + w; r < hi; r += 8) {
    ushort4 u = *(const ushort4*)(h16 + (long)r * 256 + col);
    a0 += h2f(u.x); a1 += h2f(u.y); a2 += h2f(u.z); a3 += h2f(u.w);
  }
  *(float4*)&red[w * 256 + col] = make_float4(a0, a1, a2, a3);
  __syncthreads();
  if (t < 256) {
    float s = 0.f;
#pragma unroll
    for (int j = 0; j < 8; ++j) s += red[j * 256 + t];
    int c = hi - lo;
    gpool[g * 256 + t] = s / (float)(c > 0 ? c : 1);
  }
}

// ---------------------------------------------------------------- final proj
__global__ __launch_bounds__(128) void final_k(
    const float* __restrict__ gpool, const float* __restrict__ Wp,
    const float* __restrict__ bp, float* __restrict__ out)
{
  __shared__ float gr[256];
  int g = blockIdx.x, t = threadIdx.x;
  gr[t] = gpool[g * 256 + t];
  gr[t + 128] = gpool[g * 256 + t + 128];
  __syncthreads();
  float acc = bp[t];
#pragma unroll 8
  for (int k = 0; k < 256; ++k) acc += gr[k] * Wp[k * 128 + t];
  out[g * 128 + t] = acc;
}

// ---------------------------------------------------------------- launcher
extern "C" void kernel_launch(void* const* d_in, const int* in_sizes, int n_in,
                              void* d_out, int out_size, void* d_ws, size_t ws_size,
                              hipStream_t stream)
{
  (void)in_sizes; (void)n_in; (void)out_size; (void)ws_size;
  const int* nfeat = (const int*)d_in[0];
  const int* efeat = (const int*)d_in[1];
  const int* src = (const int*)d_in[2];
  const int* dst = (const int*)d_in[3];
  const int* gid = (const int*)d_in[4];
  const float* atom_emb = (const float*)d_in[5];
  const float* edge_emb = (const float*)d_in[6];
  const float* W = (const float*)d_in[7];
  const float* b = (const float*)d_in[8];
  const float* gamma = (const float*)d_in[9];
  const float* beta = (const float*)d_in[10];
  const float* Wp = (const float*)d_in[11];
  const float* bp = (const float*)d_in[12];
  float* out = (float*)d_out;

  char* ws = (char*)d_ws;
  unsigned short* h16 = (unsigned short*)ws; ws += (size_t)N_PAD * 512;
  unsigned short* Y16 = (unsigned short*)ws; ws += (size_t)N_PAD * 512;
  unsigned short* X16 = (unsigned short*)ws; ws += (size_t)N_PAD * 512;
  unsigned short* Wt = (unsigned short*)ws; ws += 5 * 65536 * 2;
  int2* csr2 = (int2*)ws; ws += 6400000;
  int* row_start = (int*)ws; ws += 200064;
  int* degs_i = (int*)ws; ws += 200064;
  int* fill = (int*)ws; ws += 200064;
  int* cnt = (int*)ws; ws += 4800000;
  float* Pp = (float*)ws; ws += MTILES * 2 * 256 * 4;
  float* scale = (float*)ws; ws += 1024;
  float* shiftv = (float*)ws; ws += 1024;
  float* gpool = (float*)ws; ws += 131072;

  hipMemsetAsync(degs_i, 0, 200000, stream);
  hipMemsetAsync(fill, 0, 200000, stream);
  // zero X pad rows so GEMM pad output is exactly b[c]
  hipMemsetAsync(X16 + (size_t)N_NODESC * 256, 0,
                 (size_t)(N_PAD - N_NODESC) * 512, stream);

  wprep_k<<<1280, 256, 0, stream>>>(W, Wt);
  atom_encode_k<<<12500, 256, 0, stream>>>(nfeat, atom_emb, h16);
  deg_k<<<3125, 256, 0, stream>>>(dst, degs_i);
  scan_k<<<1, 1024, 0, stream>>>(degs_i, row_start, N_NODESC);
  scatter_k<<<3125, 256, 0, stream>>>(src, dst, row_start, fill, csr2);
  cnt_k<<<196, 256, 0, stream>>>(csr2, row_start, efeat, cnt);

  for (int l = 0; l < 5; ++l) {
    aggregate_k<<<12500, 256, 0, stream>>>(h16, edge_emb + l * 6144, csr2,
                                           row_start, cnt, X16);
    gemm_k<<<dim3(MTILES, 2), 256, 0, stream>>>(X16, Wt + l * 65536, b + l * 256,
                                                Y16, Pp);
    stats_finalize_k<<<1, 256, 0, stream>>>(Pp, b + l * 256, gamma + l * 256,
                                            beta + l * 256, scale, shiftv);
    bn_relu_k<<<6250, 256, 0, stream>>>(Y16, h16, scale, shiftv);
  }

  pool_k<<<128, 512, 0, stream>>>(h16, gid, gpool);
  final_k<<<128, 128, 0, stream>>>(gpool, Wp, bp, out);
}